// Round 7
// baseline (266.255 us; speedup 1.0000x reference)
//
#include <hip/hip_runtime.h>
#include <math.h>

#define B_  32
#define D_  256
#define L_  4096
#define S_  64
#define C3_ 192

#define YSZ    ((size_t)B_ * D_ * L_)   /* 33554432 */
#define HOUTSZ ((size_t)B_ * D_ * S_)   /* 524288  */
#define NCHUNK 16

typedef __attribute__((ext_vector_type(8))) short short8;
typedef __attribute__((ext_vector_type(4))) short short4v;
typedef __attribute__((ext_vector_type(4))) float f32x4;
typedef unsigned short ushort_t;
typedef unsigned int uint_t;

// hardware bf16 convert (RNE)
__device__ __forceinline__ short f2bf(float f) {
    __bf16 h = (__bf16)f;
    return __builtin_bit_cast(short, h);
}
__device__ __forceinline__ float bf2f(ushort_t u) {
    return __uint_as_float((uint_t)u << 16);
}
__device__ __forceinline__ short8 ld_cvt8(const float* p) {
    const float4* q = reinterpret_cast<const float4*>(p);
    float4 p0 = q[0], p1 = q[1];
    short8 s;
    s[0] = f2bf(p0.x); s[1] = f2bf(p0.y); s[2] = f2bf(p0.z); s[3] = f2bf(p0.w);
    s[4] = f2bf(p1.x); s[5] = f2bf(p1.y); s[6] = f2bf(p1.z); s[7] = f2bf(p1.w);
    return s;
}

// ---------------------------------------------------------------------------
// K1 (MFMA): pre_bf[b][o][l] = bf16( b_bcdt[o] + sum_d w[o][d] * x[b][d][l] )
// l-tile 64 (2048 blocks -> ~6 blocks/CU for latency hiding). A (w) in LDS,
// B (x transpose) staged via float2 loads; 12x1 frags per wave.
// ---------------------------------------------------------------------------
__global__ __launch_bounds__(256, 6) void k1_bcdt_mfma(
    const float* __restrict__ x, const float* __restrict__ w,
    const float* __restrict__ bias, ushort_t* __restrict__ out)
{
    __shared__ __align__(16) short A_lds[192][40];  // [o][k]
    __shared__ __align__(16) short B_lds[64][40];   // [l][k]
    const int l0 = blockIdx.x * 64;
    const int b  = blockIdx.y;
    const int tid  = threadIdx.x;
    const int lane = tid & 63;
    const int wv   = tid >> 6;
    const int lm   = lane & 15;
    const int kg   = lane >> 4;
    const int lp   = tid & 31;    // staging: l-pair (0..31 -> l = 2*lp)
    const int dg   = tid >> 5;    // staging: d-group of 4 (0..7)
    const float* xb = x + (size_t)b * D_ * L_;

    f32x4 acc[12];
    #pragma unroll
    for (int mi = 0; mi < 12; ++mi) acc[mi] = (f32x4){0.f, 0.f, 0.f, 0.f};

    for (int step = 0; step < 8; ++step) {
        const int k0 = step * 32;
        if (step) __syncthreads();
        // ---- stage A: w[0..192)[k0..k0+32) ----
        #pragma unroll
        for (int q = 0; q < 3; ++q) {
            int task = q * 256 + tid;
            int o = task >> 2, kk = (task & 3) * 8;
            *(short8*)&A_lds[o][kk] = ld_cvt8(w + (size_t)o * D_ + k0 + kk);
        }
        // ---- stage B: x[k0..k0+32)[l0..l0+64) -> [l][k] ----
        {
            const float* xp = xb + (size_t)(k0 + dg * 4) * L_ + l0 + lp * 2;
            float2 v[4];
            #pragma unroll
            for (int r = 0; r < 4; ++r)
                v[r] = *reinterpret_cast<const float2*>(xp + (size_t)r * L_);
            short4v s0, s1;
            #pragma unroll
            for (int r = 0; r < 4; ++r) { s0[r] = f2bf(v[r].x); s1[r] = f2bf(v[r].y); }
            *(short4v*)&B_lds[lp * 2][dg * 4]     = s0;
            *(short4v*)&B_lds[lp * 2 + 1][dg * 4] = s1;
        }
        __syncthreads();
        short8 bbf = *(const short8*)&B_lds[wv * 16 + lm][kg * 8];
        #pragma unroll
        for (int mi = 0; mi < 12; ++mi) {
            short8 a = *(const short8*)&A_lds[mi * 16 + lm][kg * 8];
            acc[mi] = __builtin_amdgcn_mfma_f32_16x16x32_bf16(a, bbf, acc[mi], 0, 0, 0);
        }
    }
    ushort_t* ob = out + (size_t)b * C3_ * L_;
    const int col = l0 + wv * 16 + lm;
    #pragma unroll
    for (int mi = 0; mi < 12; ++mi) {
        #pragma unroll
        for (int r = 0; r < 4; ++r) {
            int o = mi * 16 + kg * 4 + r;
            ob[(size_t)o * L_ + col] = (ushort_t)f2bf(acc[mi][r] + bias[o]);
        }
    }
}

// ---------------------------------------------------------------------------
// K2 fused: blockIdx.x in [0,64)  -> cm channel 64+s  (conv -> cm_bf)
//           blockIdx.x in [64,128)-> ab for s (conv dt -> softmax -> *conv Bm)
// ---------------------------------------------------------------------------
__global__ __launch_bounds__(256) void k2_conv(
    const ushort_t* __restrict__ pre, const float* __restrict__ wdw,
    const float* __restrict__ bdw, ushort_t* __restrict__ cm,
    ushort_t* __restrict__ ab)
{
    __shared__ float sm[66][66];
    __shared__ float red[4];
    const int t   = blockIdx.x;
    const int b   = blockIdx.y;
    const int s   = t & 63;
    const int tid = threadIdx.x;

    for (int i = tid; i < 66 * 66; i += 256) (&sm[0][0])[i] = 0.f;
    __syncthreads();

    if (t < 64) {
        const int c = 64 + s;
        const uint_t* ip32 = reinterpret_cast<const uint_t*>(
            pre + ((size_t)b * C3_ + c) * L_);
        for (int p2 = tid; p2 < 2048; p2 += 256) {
            uint_t v = ip32[p2];
            int q = p2 * 2;
            sm[(q >> 6) + 1][(q & 63) + 1] = bf2f((ushort_t)(v & 0xffffu));
            sm[(q >> 6) + 1][(q & 63) + 2] = bf2f((ushort_t)(v >> 16));
        }
        __syncthreads();
        const float* wp = wdw + c * 9;
        float w00 = wp[0], w01 = wp[1], w02 = wp[2],
              w10 = wp[3], w11 = wp[4], w12 = wp[5],
              w20 = wp[6], w21 = wp[7], w22 = wp[8];
        float bb = bdw[c];
        ushort_t* op = cm + ((size_t)b * S_ + s) * L_;
        for (int p = tid; p < 4096; p += 256) {
            int yy = p >> 6, xx = p & 63;
            float v = bb
                + sm[yy][xx] * w00     + sm[yy][xx + 1] * w01     + sm[yy][xx + 2] * w02
                + sm[yy + 1][xx] * w10 + sm[yy + 1][xx + 1] * w11 + sm[yy + 1][xx + 2] * w12
                + sm[yy + 2][xx] * w20 + sm[yy + 2][xx + 1] * w21 + sm[yy + 2][xx + 2] * w22;
            op[p] = (ushort_t)f2bf(v);
        }
        return;
    }

    const int cd = 128 + s;
    {
        const uint_t* ip32 = reinterpret_cast<const uint_t*>(
            pre + ((size_t)b * C3_ + cd) * L_);
        for (int p2 = tid; p2 < 2048; p2 += 256) {
            uint_t v = ip32[p2];
            int q = p2 * 2;
            sm[(q >> 6) + 1][(q & 63) + 1] = bf2f((ushort_t)(v & 0xffffu));
            sm[(q >> 6) + 1][(q & 63) + 2] = bf2f((ushort_t)(v >> 16));
        }
    }
    __syncthreads();
    float dt[16];
    {
        const float* wp = wdw + cd * 9;
        float w00 = wp[0], w01 = wp[1], w02 = wp[2],
              w10 = wp[3], w11 = wp[4], w12 = wp[5],
              w20 = wp[6], w21 = wp[7], w22 = wp[8];
        float bb = bdw[cd];
        #pragma unroll
        for (int i = 0; i < 16; ++i) {
            int p = tid + 256 * i;
            int yy = p >> 6, xx = p & 63;
            dt[i] = bb
                + sm[yy][xx] * w00     + sm[yy][xx + 1] * w01     + sm[yy][xx + 2] * w02
                + sm[yy + 1][xx] * w10 + sm[yy + 1][xx + 1] * w11 + sm[yy + 1][xx + 2] * w12
                + sm[yy + 2][xx] * w20 + sm[yy + 2][xx + 1] * w21 + sm[yy + 2][xx + 2] * w22;
        }
    }
    float mx = dt[0];
    #pragma unroll
    for (int i = 1; i < 16; ++i) mx = fmaxf(mx, dt[i]);
    #pragma unroll
    for (int off = 32; off >= 1; off >>= 1) mx = fmaxf(mx, __shfl_xor(mx, off, 64));
    if ((tid & 63) == 0) red[tid >> 6] = mx;
    __syncthreads();
    mx = fmaxf(fmaxf(red[0], red[1]), fmaxf(red[2], red[3]));
    float e[16];
    float lsum = 0.f;
    #pragma unroll
    for (int i = 0; i < 16; ++i) { e[i] = expf(dt[i] - mx); lsum += e[i]; }
    #pragma unroll
    for (int off = 32; off >= 1; off >>= 1) lsum += __shfl_xor(lsum, off, 64);
    __syncthreads();
    if ((tid & 63) == 0) red[tid >> 6] = lsum;
    __syncthreads();
    const float inv = 1.f / (red[0] + red[1] + red[2] + red[3]);
    {
        const uint_t* ip32 = reinterpret_cast<const uint_t*>(
            pre + ((size_t)b * C3_ + s) * L_);
        for (int p2 = tid; p2 < 2048; p2 += 256) {
            uint_t v = ip32[p2];
            int q = p2 * 2;
            sm[(q >> 6) + 1][(q & 63) + 1] = bf2f((ushort_t)(v & 0xffffu));
            sm[(q >> 6) + 1][(q & 63) + 2] = bf2f((ushort_t)(v >> 16));
        }
    }
    __syncthreads();
    {
        const float* wp = wdw + s * 9;
        float w00 = wp[0], w01 = wp[1], w02 = wp[2],
              w10 = wp[3], w11 = wp[4], w12 = wp[5],
              w20 = wp[6], w21 = wp[7], w22 = wp[8];
        float bb = bdw[s];
        ushort_t* op = ab + ((size_t)b * S_ + s) * L_;
        #pragma unroll
        for (int i = 0; i < 16; ++i) {
            int p = tid + 256 * i;
            int yy = p >> 6, xx = p & 63;
            float bm = bb
                + sm[yy][xx] * w00     + sm[yy][xx + 1] * w01     + sm[yy][xx + 2] * w02
                + sm[yy + 1][xx] * w10 + sm[yy + 1][xx + 1] * w11 + sm[yy + 1][xx + 2] * w12
                + sm[yy + 2][xx] * w20 + sm[yy + 2][xx + 1] * w21 + sm[yy + 2][xx + 2] * w22;
            op[p] = (ushort_t)f2bf(e[i] * inv * bm);
        }
    }
}

// ---------------------------------------------------------------------------
// K3 (MFMA, no LDS): hp[chunk][b][d][s] += x[b,d,l]*ab[b,s,l] over l-chunk 256
// x f32 (cvt in regs), ab bf16 (direct frag loads). 1024 blocks for hiding.
// ---------------------------------------------------------------------------
__global__ __launch_bounds__(256) void k3_hpart_mfma(
    const float* __restrict__ x, const ushort_t* __restrict__ ab,
    float* __restrict__ hp)
{
    const int dt    = blockIdx.x;   // 0..1
    const int b     = blockIdx.y;   // 0..31
    const int chunk = blockIdx.z;   // 0..NCHUNK-1
    const int tid  = threadIdx.x;
    const int lane = tid & 63;
    const int wv   = tid >> 6;
    const int wr   = wv >> 1, wc = wv & 1;
    const int lm   = lane & 15, kg = lane >> 4;
    const int d_base = dt * 128 + wr * 64;
    const int s_base = wc * 32;
    const float*    xb  = x  + (size_t)b * D_ * L_;
    const ushort_t* abb = ab + (size_t)b * S_ * L_;

    f32x4 acc[4][2];
    #pragma unroll
    for (int mi = 0; mi < 4; ++mi)
        #pragma unroll
        for (int nj = 0; nj < 2; ++nj)
            acc[mi][nj] = (f32x4){0.f, 0.f, 0.f, 0.f};

    #pragma unroll 2
    for (int ks = 0; ks < 8; ++ks) {
        const int l = chunk * 256 + ks * 32 + kg * 8;
        short8 bfr[2];
        #pragma unroll
        for (int nj = 0; nj < 2; ++nj)
            bfr[nj] = *reinterpret_cast<const short8*>(
                abb + (size_t)(s_base + nj * 16 + lm) * L_ + l);
        #pragma unroll
        for (int mi = 0; mi < 4; ++mi) {
            short8 a = ld_cvt8(xb + (size_t)(d_base + mi * 16 + lm) * L_ + l);
            #pragma unroll
            for (int nj = 0; nj < 2; ++nj)
                acc[mi][nj] = __builtin_amdgcn_mfma_f32_16x16x32_bf16(
                    a, bfr[nj], acc[mi][nj], 0, 0, 0);
        }
    }
    float* hpo = hp + (size_t)chunk * HOUTSZ + (size_t)b * D_ * S_;
    #pragma unroll
    for (int mi = 0; mi < 4; ++mi)
        #pragma unroll
        for (int r = 0; r < 4; ++r) {
            int d = d_base + mi * 16 + kg * 4 + r;
            #pragma unroll
            for (int nj = 0; nj < 2; ++nj)
                hpo[(size_t)d * S_ + s_base + nj * 16 + lm] = acc[mi][nj][r];
        }
}

// ---------------------------------------------------------------------------
// K4a: h = sum_chunk hp (fused); hz = w_hz @ h + b_hz; g = h2*(silu(z)+D)
// ---------------------------------------------------------------------------
__global__ __launch_bounds__(256) void k4a_gate(
    const float* __restrict__ hp, const float* __restrict__ whz,
    const float* __restrict__ bhz, const float* __restrict__ Dp,
    float* __restrict__ g)
{
    __shared__ float Ah[16][68];
    __shared__ float Az[16][68];
    __shared__ float Bs[16][64];
    const int o0 = blockIdx.x * 64;
    const int b  = blockIdx.y;
    const int tid = threadIdx.x;
    const int tx = tid & 15, ty = tid >> 4;
    float acch[4][4] = {}, accz[4][4] = {};
    const float* hb = hp + (size_t)b * D_ * S_;
    for (int k0 = 0; k0 < D_; k0 += 16) {
        {
            int o = tid & 15, k = tid >> 4;
            #pragma unroll
            for (int i = 0; i < 4; ++i) {
                Ah[k][o + 16 * i] = whz[(size_t)(o0 + o + 16 * i) * D_ + k0 + k];
                Az[k][o + 16 * i] = whz[(size_t)(o0 + o + 16 * i + 256) * D_ + k0 + k];
            }
        }
        {
            int s = tid & 63, k = tid >> 6;
            #pragma unroll
            for (int i = 0; i < 4; ++i) {
                float sum = 0.f;
                #pragma unroll
                for (int c = 0; c < NCHUNK; ++c)
                    sum += hb[(size_t)c * HOUTSZ + (size_t)(k0 + k + 4 * i) * S_ + s];
                Bs[k + 4 * i][s] = sum;
            }
        }
        __syncthreads();
        #pragma unroll
        for (int k = 0; k < 16; ++k) {
            float ah[4], az[4], bb[4];
            #pragma unroll
            for (int i = 0; i < 4; ++i) { ah[i] = Ah[k][ty * 4 + i]; az[i] = Az[k][ty * 4 + i]; }
            #pragma unroll
            for (int j = 0; j < 4; ++j) bb[j] = Bs[k][tx * 4 + j];
            #pragma unroll
            for (int i = 0; i < 4; ++i)
                #pragma unroll
                for (int j = 0; j < 4; ++j) {
                    acch[i][j] += ah[i] * bb[j];
                    accz[i][j] += az[i] * bb[j];
                }
        }
        __syncthreads();
    }
    const float dp = Dp[0];
    #pragma unroll
    for (int i = 0; i < 4; ++i) {
        int o = o0 + ty * 4 + i;
        float bh = bhz[o], bz = bhz[o + 256];
        #pragma unroll
        for (int j = 0; j < 4; ++j) {
            float h2 = acch[i][j] + bh;
            float z  = accz[i][j] + bz;
            float sil = z / (1.f + expf(-z));
            g[((size_t)b * D_ + o) * S_ + tx * 4 + j] = h2 * (sil + dp);
        }
    }
}

// ---------------------------------------------------------------------------
// K4b: hout = w_out @ g + b_out -> d_out (output 1)
// ---------------------------------------------------------------------------
__global__ __launch_bounds__(256) void k4b_hout(
    const float* __restrict__ g, const float* __restrict__ wout,
    const float* __restrict__ bout, float* __restrict__ hout)
{
    __shared__ float At[16][68];
    __shared__ float Bs[16][64];
    const int o0 = blockIdx.x * 64;
    const int b  = blockIdx.y;
    const int tid = threadIdx.x;
    const int tx = tid & 15, ty = tid >> 4;
    float acc[4][4] = {};
    const float* gb = g + (size_t)b * D_ * S_;
    for (int k0 = 0; k0 < D_; k0 += 16) {
        {
            int o = tid & 15, k = tid >> 4;
            #pragma unroll
            for (int i = 0; i < 4; ++i)
                At[k][o + 16 * i] = wout[(size_t)(o0 + o + 16 * i) * D_ + k0 + k];
        }
        {
            int s = tid & 63, k = tid >> 6;
            #pragma unroll
            for (int i = 0; i < 4; ++i)
                Bs[k + 4 * i][s] = gb[(size_t)(k0 + k + 4 * i) * S_ + s];
        }
        __syncthreads();
        #pragma unroll
        for (int k = 0; k < 16; ++k) {
            float a[4], bb[4];
            #pragma unroll
            for (int i = 0; i < 4; ++i) a[i] = At[k][ty * 4 + i];
            #pragma unroll
            for (int j = 0; j < 4; ++j) bb[j] = Bs[k][tx * 4 + j];
            #pragma unroll
            for (int i = 0; i < 4; ++i)
                #pragma unroll
                for (int j = 0; j < 4; ++j)
                    acc[i][j] += a[i] * bb[j];
        }
        __syncthreads();
    }
    #pragma unroll
    for (int i = 0; i < 4; ++i) {
        int o = o0 + ty * 4 + i;
        float bv = bout[o];
        #pragma unroll
        for (int j = 0; j < 4; ++j)
            hout[((size_t)b * D_ + o) * S_ + tx * 4 + j] = acc[i][j] + bv;
    }
}

// ---------------------------------------------------------------------------
// K5 (MFMA): y[b][d][l] = sum_s hout[b][d][s] * cm_bf[b][s][l]
// ---------------------------------------------------------------------------
__global__ __launch_bounds__(256) void k5_expand_mfma(
    const float* __restrict__ hout, const ushort_t* __restrict__ cm,
    float* __restrict__ y)
{
    __shared__ __align__(16) short A_lds[64][72];   // [d][s]
    __shared__ __align__(16) short B_lds[128][72];  // [l][s]
    const int l0 = blockIdx.x * 128;
    const int d0 = blockIdx.y * 64;
    const int b  = blockIdx.z;
    const int tid  = threadIdx.x;
    const int lane = tid & 63;
    const int wv   = tid >> 6;
    const int lm   = lane & 15, kg = lane >> 4;

    #pragma unroll
    for (int q = 0; q < 2; ++q) {
        int task = q * 256 + tid;
        int d = task >> 3, sg = (task & 7) * 8;
        *(short8*)&A_lds[d][sg] = ld_cvt8(hout + ((size_t)b * D_ + d0 + d) * S_ + sg);
    }
    #pragma unroll
    for (int q = 0; q < 4; ++q) {
        int l = tid & 127;
        int sg = (q * 2 + (tid >> 7)) * 8;
        const ushort_t* cp = cm + ((size_t)b * S_ + sg) * L_ + l0 + l;
        short8 s;
        #pragma unroll
        for (int r = 0; r < 8; ++r) s[r] = (short)cp[(size_t)r * L_];
        *(short8*)&B_lds[l][sg] = s;
    }
    __syncthreads();

    f32x4 acc[4][2];
    #pragma unroll
    for (int mi = 0; mi < 4; ++mi)
        #pragma unroll
        for (int nj = 0; nj < 2; ++nj)
            acc[mi][nj] = (f32x4){0.f, 0.f, 0.f, 0.f};
    #pragma unroll
    for (int ks = 0; ks < 2; ++ks) {
        short8 bb[2];
        #pragma unroll
        for (int nj = 0; nj < 2; ++nj)
            bb[nj] = *(const short8*)&B_lds[wv * 32 + nj * 16 + lm][ks * 32 + kg * 8];
        #pragma unroll
        for (int mi = 0; mi < 4; ++mi) {
            short8 a = *(const short8*)&A_lds[mi * 16 + lm][ks * 32 + kg * 8];
            #pragma unroll
            for (int nj = 0; nj < 2; ++nj)
                acc[mi][nj] = __builtin_amdgcn_mfma_f32_16x16x32_bf16(
                    a, bb[nj], acc[mi][nj], 0, 0, 0);
        }
    }
    const int col = l0 + wv * 32 + lm;
    #pragma unroll
    for (int mi = 0; mi < 4; ++mi)
        #pragma unroll
        for (int r = 0; r < 4; ++r)
            #pragma unroll
            for (int nj = 0; nj < 2; ++nj)
                y[((size_t)b * D_ + d0 + mi * 16 + kg * 4 + r) * L_ + col + nj * 16]
                    = acc[mi][nj][r];
}

// ---------------------------------------------------------------------------
extern "C" void kernel_launch(void* const* d_in, const int* in_sizes, int n_in,
                              void* d_out, int out_size, void* d_ws, size_t ws_size,
                              hipStream_t stream)
{
    const float* x      = (const float*)d_in[0];
    const float* w_bcdt = (const float*)d_in[3];
    const float* b_bcdt = (const float*)d_in[4];
    const float* w_dw   = (const float*)d_in[5];
    const float* b_dw   = (const float*)d_in[6];
    const float* w_hz   = (const float*)d_in[7];
    const float* b_hz   = (const float*)d_in[8];
    const float* w_out  = (const float*)d_in[9];
    const float* b_out  = (const float*)d_in[10];
    // d_in[11] = A_param: constant along softmax axis L -> cancels, unused
    const float* Dp     = (const float*)d_in[12];

    char* base = (char*)d_ws;
    ushort_t* pre_bf = (ushort_t*)(base);                    // 50.3 MB
    ushort_t* ab_bf  = (ushort_t*)(base + 50331648);         // 16.8 MB
    ushort_t* cm_bf  = (ushort_t*)(base + 67108864);         // 16.8 MB
    float*    hp     = (float*)   (base + 83886080);         // 16*2 MB = 33.5 MB
    float*    g      = (float*)   (base + 117440512);        //  2.1 MB

    float* y    = (float*)d_out;
    float* hout = (float*)d_out + YSZ;

    k1_bcdt_mfma  <<<dim3(64, 32),        256, 0, stream>>>(x, w_bcdt, b_bcdt, pre_bf);
    k2_conv       <<<dim3(128, 32),       256, 0, stream>>>(pre_bf, w_dw, b_dw, cm_bf, ab_bf);
    k3_hpart_mfma <<<dim3(2, 32, NCHUNK), 256, 0, stream>>>(x, ab_bf, hp);
    k4a_gate      <<<dim3(4, 32),         256, 0, stream>>>(hp, w_hz, b_hz, Dp, g);
    k4b_hout      <<<dim3(4, 32),         256, 0, stream>>>(g, w_out, b_out, hout);
    k5_expand_mfma<<<dim3(32, 4, 32),     256, 0, stream>>>(hout, cm_bf, y);
}

// Round 8
// 216.339 us; speedup vs baseline: 1.2307x; 1.2307x over previous
//
#include <hip/hip_runtime.h>
#include <math.h>

#define B_  32
#define D_  256
#define L_  4096
#define S_  64
#define C3_ 192

#define YSZ    ((size_t)B_ * D_ * L_)   /* 33554432 */
#define HOUTSZ ((size_t)B_ * D_ * S_)   /* 524288  */
#define NCHUNK 8

typedef __attribute__((ext_vector_type(8))) short short8;
typedef __attribute__((ext_vector_type(4))) float f32x4;
typedef unsigned short ushort_t;
typedef unsigned int uint_t;

// hardware bf16 convert (RNE)
__device__ __forceinline__ short f2bf(float f) {
    __bf16 h = (__bf16)f;
    return __builtin_bit_cast(short, h);
}
__device__ __forceinline__ float bf2f(ushort_t u) {
    return __uint_as_float((uint_t)u << 16);
}
__device__ __forceinline__ short8 ld_cvt8(const float* p) {
    const float4* q = reinterpret_cast<const float4*>(p);
    float4 p0 = q[0], p1 = q[1];
    short8 s;
    s[0] = f2bf(p0.x); s[1] = f2bf(p0.y); s[2] = f2bf(p0.z); s[3] = f2bf(p0.w);
    s[4] = f2bf(p1.x); s[5] = f2bf(p1.y); s[6] = f2bf(p1.z); s[7] = f2bf(p1.w);
    return s;
}

// ---------------------------------------------------------------------------
// K1 (MFMA): pre_bf[b][o][l] = bf16( b_bcdt[o] + sum_d w[o][d] * x[b][d][l] )
// EXACT R5 structure (best known: ~45 us). 128 l-tile, A+B in LDS, 2 barriers.
// ---------------------------------------------------------------------------
__global__ __launch_bounds__(256) void k1_bcdt_mfma(
    const float* __restrict__ x, const float* __restrict__ w,
    const float* __restrict__ bias, ushort_t* __restrict__ out)
{
    __shared__ __align__(16) short A_lds[192][40];  // [o][k]
    __shared__ __align__(16) short B_lds[128][40];  // [l][k]
    const int l0 = blockIdx.x * 128;
    const int b  = blockIdx.y;
    const int tid  = threadIdx.x;
    const int lane = tid & 63;
    const int wv   = tid >> 6;
    const int lm   = lane & 15;
    const int kg   = lane >> 4;
    const float* xb = x + (size_t)b * D_ * L_;

    f32x4 acc[12][2];
    #pragma unroll
    for (int mi = 0; mi < 12; ++mi)
        #pragma unroll
        for (int nj = 0; nj < 2; ++nj)
            acc[mi][nj] = (f32x4){0.f, 0.f, 0.f, 0.f};

    for (int k0 = 0; k0 < D_; k0 += 32) {
        if (k0) __syncthreads();
        // ---- stage A: w[0..192)[k0..k0+32) ----
        #pragma unroll
        for (int q = 0; q < 3; ++q) {
            int task = q * 256 + tid;
            int o = task >> 2, kk = (task & 3) * 8;
            *(short8*)&A_lds[o][kk] = ld_cvt8(w + (size_t)o * D_ + k0 + kk);
        }
        // ---- stage B: x[k0..k0+32)[l0..l0+128) -> [l][k], float2 loads ----
        {
            int lp = tid & 63;            // l-pair
            int kgs = tid >> 6;           // k-group of 8
            const float* xp = xb + (size_t)(k0 + kgs * 8) * L_ + l0 + lp * 2;
            float2 v[8];
            #pragma unroll
            for (int r = 0; r < 8; ++r)
                v[r] = *reinterpret_cast<const float2*>(xp + (size_t)r * L_);
            short8 s0, s1;
            #pragma unroll
            for (int r = 0; r < 8; ++r) { s0[r] = f2bf(v[r].x); s1[r] = f2bf(v[r].y); }
            *(short8*)&B_lds[lp * 2][kgs * 8]     = s0;
            *(short8*)&B_lds[lp * 2 + 1][kgs * 8] = s1;
        }
        __syncthreads();
        short8 bb[2];
        #pragma unroll
        for (int nj = 0; nj < 2; ++nj)
            bb[nj] = *(const short8*)&B_lds[wv * 32 + nj * 16 + lm][kg * 8];
        #pragma unroll
        for (int mi = 0; mi < 12; ++mi) {
            short8 a = *(const short8*)&A_lds[mi * 16 + lm][kg * 8];
            #pragma unroll
            for (int nj = 0; nj < 2; ++nj)
                acc[mi][nj] = __builtin_amdgcn_mfma_f32_16x16x32_bf16(
                    a, bb[nj], acc[mi][nj], 0, 0, 0);
        }
    }
    ushort_t* ob = out + (size_t)b * C3_ * L_;
    const int col = l0 + wv * 32 + lm;
    #pragma unroll
    for (int mi = 0; mi < 12; ++mi) {
        #pragma unroll
        for (int r = 0; r < 4; ++r) {
            int o = mi * 16 + kg * 4 + r;
            float bv = bias[o];
            #pragma unroll
            for (int nj = 0; nj < 2; ++nj)
                ob[(size_t)o * L_ + col + nj * 16] =
                    (ushort_t)f2bf(acc[mi][nj][r] + bv);
        }
    }
}

// ---------------------------------------------------------------------------
// K2 fused: blockIdx.x in [0,64)  -> cm channel 64+s  (conv -> cm_bf)
//           blockIdx.x in [64,128)-> ab for s (conv dt -> softmax -> *conv Bm)
// ---------------------------------------------------------------------------
__global__ __launch_bounds__(256) void k2_conv(
    const ushort_t* __restrict__ pre, const float* __restrict__ wdw,
    const float* __restrict__ bdw, ushort_t* __restrict__ cm,
    ushort_t* __restrict__ ab)
{
    __shared__ float sm[66][66];
    __shared__ float red[4];
    const int t   = blockIdx.x;
    const int b   = blockIdx.y;
    const int s   = t & 63;
    const int tid = threadIdx.x;

    for (int i = tid; i < 66 * 66; i += 256) (&sm[0][0])[i] = 0.f;
    __syncthreads();

    if (t < 64) {
        const int c = 64 + s;
        const uint_t* ip32 = reinterpret_cast<const uint_t*>(
            pre + ((size_t)b * C3_ + c) * L_);
        for (int p2 = tid; p2 < 2048; p2 += 256) {
            uint_t v = ip32[p2];
            int q = p2 * 2;
            sm[(q >> 6) + 1][(q & 63) + 1] = bf2f((ushort_t)(v & 0xffffu));
            sm[(q >> 6) + 1][(q & 63) + 2] = bf2f((ushort_t)(v >> 16));
        }
        __syncthreads();
        const float* wp = wdw + c * 9;
        float w00 = wp[0], w01 = wp[1], w02 = wp[2],
              w10 = wp[3], w11 = wp[4], w12 = wp[5],
              w20 = wp[6], w21 = wp[7], w22 = wp[8];
        float bb = bdw[c];
        ushort_t* op = cm + ((size_t)b * S_ + s) * L_;
        for (int p = tid; p < 4096; p += 256) {
            int yy = p >> 6, xx = p & 63;
            float v = bb
                + sm[yy][xx] * w00     + sm[yy][xx + 1] * w01     + sm[yy][xx + 2] * w02
                + sm[yy + 1][xx] * w10 + sm[yy + 1][xx + 1] * w11 + sm[yy + 1][xx + 2] * w12
                + sm[yy + 2][xx] * w20 + sm[yy + 2][xx + 1] * w21 + sm[yy + 2][xx + 2] * w22;
            op[p] = (ushort_t)f2bf(v);
        }
        return;
    }

    const int cd = 128 + s;
    {
        const uint_t* ip32 = reinterpret_cast<const uint_t*>(
            pre + ((size_t)b * C3_ + cd) * L_);
        for (int p2 = tid; p2 < 2048; p2 += 256) {
            uint_t v = ip32[p2];
            int q = p2 * 2;
            sm[(q >> 6) + 1][(q & 63) + 1] = bf2f((ushort_t)(v & 0xffffu));
            sm[(q >> 6) + 1][(q & 63) + 2] = bf2f((ushort_t)(v >> 16));
        }
    }
    __syncthreads();
    float dt[16];
    {
        const float* wp = wdw + cd * 9;
        float w00 = wp[0], w01 = wp[1], w02 = wp[2],
              w10 = wp[3], w11 = wp[4], w12 = wp[5],
              w20 = wp[6], w21 = wp[7], w22 = wp[8];
        float bb = bdw[cd];
        #pragma unroll
        for (int i = 0; i < 16; ++i) {
            int p = tid + 256 * i;
            int yy = p >> 6, xx = p & 63;
            dt[i] = bb
                + sm[yy][xx] * w00     + sm[yy][xx + 1] * w01     + sm[yy][xx + 2] * w02
                + sm[yy + 1][xx] * w10 + sm[yy + 1][xx + 1] * w11 + sm[yy + 1][xx + 2] * w12
                + sm[yy + 2][xx] * w20 + sm[yy + 2][xx + 1] * w21 + sm[yy + 2][xx + 2] * w22;
        }
    }
    float mx = dt[0];
    #pragma unroll
    for (int i = 1; i < 16; ++i) mx = fmaxf(mx, dt[i]);
    #pragma unroll
    for (int off = 32; off >= 1; off >>= 1) mx = fmaxf(mx, __shfl_xor(mx, off, 64));
    if ((tid & 63) == 0) red[tid >> 6] = mx;
    __syncthreads();
    mx = fmaxf(fmaxf(red[0], red[1]), fmaxf(red[2], red[3]));
    float e[16];
    float lsum = 0.f;
    #pragma unroll
    for (int i = 0; i < 16; ++i) { e[i] = expf(dt[i] - mx); lsum += e[i]; }
    #pragma unroll
    for (int off = 32; off >= 1; off >>= 1) lsum += __shfl_xor(lsum, off, 64);
    __syncthreads();
    if ((tid & 63) == 0) red[tid >> 6] = lsum;
    __syncthreads();
    const float inv = 1.f / (red[0] + red[1] + red[2] + red[3]);
    {
        const uint_t* ip32 = reinterpret_cast<const uint_t*>(
            pre + ((size_t)b * C3_ + s) * L_);
        for (int p2 = tid; p2 < 2048; p2 += 256) {
            uint_t v = ip32[p2];
            int q = p2 * 2;
            sm[(q >> 6) + 1][(q & 63) + 1] = bf2f((ushort_t)(v & 0xffffu));
            sm[(q >> 6) + 1][(q & 63) + 2] = bf2f((ushort_t)(v >> 16));
        }
    }
    __syncthreads();
    {
        const float* wp = wdw + s * 9;
        float w00 = wp[0], w01 = wp[1], w02 = wp[2],
              w10 = wp[3], w11 = wp[4], w12 = wp[5],
              w20 = wp[6], w21 = wp[7], w22 = wp[8];
        float bb = bdw[s];
        ushort_t* op = ab + ((size_t)b * S_ + s) * L_;
        #pragma unroll
        for (int i = 0; i < 16; ++i) {
            int p = tid + 256 * i;
            int yy = p >> 6, xx = p & 63;
            float bm = bb
                + sm[yy][xx] * w00     + sm[yy][xx + 1] * w01     + sm[yy][xx + 2] * w02
                + sm[yy + 1][xx] * w10 + sm[yy + 1][xx + 1] * w11 + sm[yy + 1][xx + 2] * w12
                + sm[yy + 2][xx] * w20 + sm[yy + 2][xx + 1] * w21 + sm[yy + 2][xx + 2] * w22;
            op[p] = (ushort_t)f2bf(e[i] * inv * bm);
        }
    }
}

// ---------------------------------------------------------------------------
// K3 (MFMA, no LDS): hp[chunk][b][d][s] += x[b,d,l]*ab[b,s,l] over l-chunk 512
// ---------------------------------------------------------------------------
__global__ __launch_bounds__(256) void k3_hpart_mfma(
    const float* __restrict__ x, const ushort_t* __restrict__ ab,
    float* __restrict__ hp)
{
    const int dt    = blockIdx.x;   // 0..1
    const int b     = blockIdx.y;   // 0..31
    const int chunk = blockIdx.z;   // 0..NCHUNK-1
    const int tid  = threadIdx.x;
    const int lane = tid & 63;
    const int wv   = tid >> 6;
    const int wr   = wv >> 1, wc = wv & 1;
    const int lm   = lane & 15, kg = lane >> 4;
    const int d_base = dt * 128 + wr * 64;
    const int s_base = wc * 32;
    const float*    xb  = x  + (size_t)b * D_ * L_;
    const ushort_t* abb = ab + (size_t)b * S_ * L_;

    f32x4 acc[4][2];
    #pragma unroll
    for (int mi = 0; mi < 4; ++mi)
        #pragma unroll
        for (int nj = 0; nj < 2; ++nj)
            acc[mi][nj] = (f32x4){0.f, 0.f, 0.f, 0.f};

    #pragma unroll 2
    for (int ks = 0; ks < 16; ++ks) {
        const int l = chunk * 512 + ks * 32 + kg * 8;
        short8 bfr[2];
        #pragma unroll
        for (int nj = 0; nj < 2; ++nj)
            bfr[nj] = *reinterpret_cast<const short8*>(
                abb + (size_t)(s_base + nj * 16 + lm) * L_ + l);
        #pragma unroll
        for (int mi = 0; mi < 4; ++mi) {
            short8 a = ld_cvt8(xb + (size_t)(d_base + mi * 16 + lm) * L_ + l);
            #pragma unroll
            for (int nj = 0; nj < 2; ++nj)
                acc[mi][nj] = __builtin_amdgcn_mfma_f32_16x16x32_bf16(
                    a, bfr[nj], acc[mi][nj], 0, 0, 0);
        }
    }
    float* hpo = hp + (size_t)chunk * HOUTSZ + (size_t)b * D_ * S_;
    #pragma unroll
    for (int mi = 0; mi < 4; ++mi)
        #pragma unroll
        for (int r = 0; r < 4; ++r) {
            int d = d_base + mi * 16 + kg * 4 + r;
            #pragma unroll
            for (int nj = 0; nj < 2; ++nj)
                hpo[(size_t)d * S_ + s_base + nj * 16 + lm] = acc[mi][nj][r];
        }
}

// ---------------------------------------------------------------------------
// K4a: h = sum_chunk hp (fused); hz = w_hz @ h + b_hz; g = h2*(silu(z)+D)
// ---------------------------------------------------------------------------
__global__ __launch_bounds__(256) void k4a_gate(
    const float* __restrict__ hp, const float* __restrict__ whz,
    const float* __restrict__ bhz, const float* __restrict__ Dp,
    float* __restrict__ g)
{
    __shared__ float Ah[16][68];
    __shared__ float Az[16][68];
    __shared__ float Bs[16][64];
    const int o0 = blockIdx.x * 64;
    const int b  = blockIdx.y;
    const int tid = threadIdx.x;
    const int tx = tid & 15, ty = tid >> 4;
    float acch[4][4] = {}, accz[4][4] = {};
    const float* hb = hp + (size_t)b * D_ * S_;
    for (int k0 = 0; k0 < D_; k0 += 16) {
        {
            int o = tid & 15, k = tid >> 4;
            #pragma unroll
            for (int i = 0; i < 4; ++i) {
                Ah[k][o + 16 * i] = whz[(size_t)(o0 + o + 16 * i) * D_ + k0 + k];
                Az[k][o + 16 * i] = whz[(size_t)(o0 + o + 16 * i + 256) * D_ + k0 + k];
            }
        }
        {
            int s = tid & 63, k = tid >> 6;
            #pragma unroll
            for (int i = 0; i < 4; ++i) {
                float sum = 0.f;
                #pragma unroll
                for (int c = 0; c < NCHUNK; ++c)
                    sum += hb[(size_t)c * HOUTSZ + (size_t)(k0 + k + 4 * i) * S_ + s];
                Bs[k + 4 * i][s] = sum;
            }
        }
        __syncthreads();
        #pragma unroll
        for (int k = 0; k < 16; ++k) {
            float ah[4], az[4], bb[4];
            #pragma unroll
            for (int i = 0; i < 4; ++i) { ah[i] = Ah[k][ty * 4 + i]; az[i] = Az[k][ty * 4 + i]; }
            #pragma unroll
            for (int j = 0; j < 4; ++j) bb[j] = Bs[k][tx * 4 + j];
            #pragma unroll
            for (int i = 0; i < 4; ++i)
                #pragma unroll
                for (int j = 0; j < 4; ++j) {
                    acch[i][j] += ah[i] * bb[j];
                    accz[i][j] += az[i] * bb[j];
                }
        }
        __syncthreads();
    }
    const float dp = Dp[0];
    #pragma unroll
    for (int i = 0; i < 4; ++i) {
        int o = o0 + ty * 4 + i;
        float bh = bhz[o], bz = bhz[o + 256];
        #pragma unroll
        for (int j = 0; j < 4; ++j) {
            float h2 = acch[i][j] + bh;
            float z  = accz[i][j] + bz;
            float sil = z / (1.f + expf(-z));
            g[((size_t)b * D_ + o) * S_ + tx * 4 + j] = h2 * (sil + dp);
        }
    }
}

// ---------------------------------------------------------------------------
// K4b: hout = w_out @ g + b_out -> d_out (output 1)
// ---------------------------------------------------------------------------
__global__ __launch_bounds__(256) void k4b_hout(
    const float* __restrict__ g, const float* __restrict__ wout,
    const float* __restrict__ bout, float* __restrict__ hout)
{
    __shared__ float At[16][68];
    __shared__ float Bs[16][64];
    const int o0 = blockIdx.x * 64;
    const int b  = blockIdx.y;
    const int tid = threadIdx.x;
    const int tx = tid & 15, ty = tid >> 4;
    float acc[4][4] = {};
    const float* gb = g + (size_t)b * D_ * S_;
    for (int k0 = 0; k0 < D_; k0 += 16) {
        {
            int o = tid & 15, k = tid >> 4;
            #pragma unroll
            for (int i = 0; i < 4; ++i)
                At[k][o + 16 * i] = wout[(size_t)(o0 + o + 16 * i) * D_ + k0 + k];
        }
        {
            int s = tid & 63, k = tid >> 6;
            #pragma unroll
            for (int i = 0; i < 4; ++i)
                Bs[k + 4 * i][s] = gb[(size_t)(k0 + k + 4 * i) * S_ + s];
        }
        __syncthreads();
        #pragma unroll
        for (int k = 0; k < 16; ++k) {
            float a[4], bb[4];
            #pragma unroll
            for (int i = 0; i < 4; ++i) a[i] = At[k][ty * 4 + i];
            #pragma unroll
            for (int j = 0; j < 4; ++j) bb[j] = Bs[k][tx * 4 + j];
            #pragma unroll
            for (int i = 0; i < 4; ++i)
                #pragma unroll
                for (int j = 0; j < 4; ++j)
                    acc[i][j] += a[i] * bb[j];
        }
        __syncthreads();
    }
    #pragma unroll
    for (int i = 0; i < 4; ++i) {
        int o = o0 + ty * 4 + i;
        float bv = bout[o];
        #pragma unroll
        for (int j = 0; j < 4; ++j)
            hout[((size_t)b * D_ + o) * S_ + tx * 4 + j] = acc[i][j] + bv;
    }
}

// ---------------------------------------------------------------------------
// K5 (MFMA): y[b][d][l] = sum_s hout[b][d][s] * cm_bf[b][s][l]
// d-tile 128 (was 64): halves cm re-reads. Grid (32 l, 2 d, 32 b).
// ---------------------------------------------------------------------------
__global__ __launch_bounds__(256) void k5_expand_mfma(
    const float* __restrict__ hout, const ushort_t* __restrict__ cm,
    float* __restrict__ y)
{
    __shared__ __align__(16) short A_lds[128][72];  // [d][s]
    __shared__ __align__(16) short B_lds[128][72];  // [l][s]
    const int l0 = blockIdx.x * 128;
    const int d0 = blockIdx.y * 128;
    const int b  = blockIdx.z;
    const int tid  = threadIdx.x;
    const int lane = tid & 63;
    const int wv   = tid >> 6;
    const int lm   = lane & 15, kg = lane >> 4;

    // stage A: hout[b][d0..d0+128][0..64] (coalesced float4 pairs)
    #pragma unroll
    for (int q = 0; q < 4; ++q) {
        int task = q * 256 + tid;              // 0..1023
        int d = task >> 3, sg = (task & 7) * 8;
        *(short8*)&A_lds[d][sg] = ld_cvt8(hout + ((size_t)b * D_ + d0 + d) * S_ + sg);
    }
    // stage B: cm[b][s][l0..l0+128] transposed -> [l][s]
    #pragma unroll
    for (int q = 0; q < 4; ++q) {
        int l = tid & 127;
        int sg = (q * 2 + (tid >> 7)) * 8;
        const ushort_t* cp = cm + ((size_t)b * S_ + sg) * L_ + l0 + l;
        short8 s;
        #pragma unroll
        for (int r = 0; r < 8; ++r) s[r] = (short)cp[(size_t)r * L_];
        *(short8*)&B_lds[l][sg] = s;
    }
    __syncthreads();

    f32x4 acc[8][2];
    #pragma unroll
    for (int mi = 0; mi < 8; ++mi)
        #pragma unroll
        for (int nj = 0; nj < 2; ++nj)
            acc[mi][nj] = (f32x4){0.f, 0.f, 0.f, 0.f};
    #pragma unroll
    for (int ks = 0; ks < 2; ++ks) {
        short8 bb[2];
        #pragma unroll
        for (int nj = 0; nj < 2; ++nj)
            bb[nj] = *(const short8*)&B_lds[wv * 32 + nj * 16 + lm][ks * 32 + kg * 8];
        #pragma unroll
        for (int mi = 0; mi < 8; ++mi) {
            short8 a = *(const short8*)&A_lds[mi * 16 + lm][ks * 32 + kg * 8];
            #pragma unroll
            for (int nj = 0; nj < 2; ++nj)
                acc[mi][nj] = __builtin_amdgcn_mfma_f32_16x16x32_bf16(
                    a, bb[nj], acc[mi][nj], 0, 0, 0);
        }
    }
    const int col = l0 + wv * 32 + lm;
    #pragma unroll
    for (int mi = 0; mi < 8; ++mi)
        #pragma unroll
        for (int r = 0; r < 4; ++r)
            #pragma unroll
            for (int nj = 0; nj < 2; ++nj)
                y[((size_t)b * D_ + d0 + mi * 16 + kg * 4 + r) * L_ + col + nj * 16]
                    = acc[mi][nj][r];
}

// ---------------------------------------------------------------------------
extern "C" void kernel_launch(void* const* d_in, const int* in_sizes, int n_in,
                              void* d_out, int out_size, void* d_ws, size_t ws_size,
                              hipStream_t stream)
{
    const float* x      = (const float*)d_in[0];
    const float* w_bcdt = (const float*)d_in[3];
    const float* b_bcdt = (const float*)d_in[4];
    const float* w_dw   = (const float*)d_in[5];
    const float* b_dw   = (const float*)d_in[6];
    const float* w_hz   = (const float*)d_in[7];
    const float* b_hz   = (const float*)d_in[8];
    const float* w_out  = (const float*)d_in[9];
    const float* b_out  = (const float*)d_in[10];
    // d_in[11] = A_param: constant along softmax axis L -> cancels, unused
    const float* Dp     = (const float*)d_in[12];

    char* base = (char*)d_ws;
    ushort_t* pre_bf = (ushort_t*)(base);                    // 50.3 MB
    ushort_t* ab_bf  = (ushort_t*)(base + 50331648);         // 16.8 MB
    ushort_t* cm_bf  = (ushort_t*)(base + 67108864);         // 16.8 MB
    float*    hp     = (float*)   (base + 83886080);         // 8*2 MB = 16.8 MB
    float*    g      = (float*)   (base + 100663296);        //  2.1 MB

    float* y    = (float*)d_out;
    float* hout = (float*)d_out + YSZ;

    k1_bcdt_mfma  <<<dim3(32, 32),        256, 0, stream>>>(x, w_bcdt, b_bcdt, pre_bf);
    k2_conv       <<<dim3(128, 32),       256, 0, stream>>>(pre_bf, w_dw, b_dw, cm_bf, ab_bf);
    k3_hpart_mfma <<<dim3(2, 32, NCHUNK), 256, 0, stream>>>(x, ab_bf, hp);
    k4a_gate      <<<dim3(4, 32),         256, 0, stream>>>(hp, w_hz, b_hz, Dp, g);
    k4b_hout      <<<dim3(4, 32),         256, 0, stream>>>(g, w_out, b_out, hout);
    k5_expand_mfma<<<dim3(32, 2, 32),     256, 0, stream>>>(hout, cm_bf, y);
}

// Round 9
// 212.638 us; speedup vs baseline: 1.2522x; 1.0174x over previous
//
#include <hip/hip_runtime.h>
#include <math.h>

#define B_  32
#define D_  256
#define L_  4096
#define S_  64
#define C3_ 192

#define YSZ    ((size_t)B_ * D_ * L_)   /* 33554432 */
#define HOUTSZ ((size_t)B_ * D_ * S_)   /* 524288  */
#define NCHUNK 8

typedef __attribute__((ext_vector_type(8))) short short8;
typedef __attribute__((ext_vector_type(4))) float f32x4;
typedef unsigned short ushort_t;
typedef unsigned int uint_t;

// hardware bf16 convert (RNE)
__device__ __forceinline__ short f2bf(float f) {
    __bf16 h = (__bf16)f;
    return __builtin_bit_cast(short, h);
}
__device__ __forceinline__ float bf2f(ushort_t u) {
    return __uint_as_float((uint_t)u << 16);
}
__device__ __forceinline__ short8 ld_cvt8(const float* p) {
    const float4* q = reinterpret_cast<const float4*>(p);
    float4 p0 = q[0], p1 = q[1];
    short8 s;
    s[0] = f2bf(p0.x); s[1] = f2bf(p0.y); s[2] = f2bf(p0.z); s[3] = f2bf(p0.w);
    s[4] = f2bf(p1.x); s[5] = f2bf(p1.y); s[6] = f2bf(p1.z); s[7] = f2bf(p1.w);
    return s;
}

// ---------------------------------------------------------------------------
// K1 (MFMA): pre_bf[b][o][l] = bf16( b_bcdt[o] + sum_d w[o][d] * x[b][d][l] )
// R5 structure; waves remapped 2x2 (96 rows x 64 cols each):
// LDS reads/step/wave 14 -> 10 (6 A + 4 B), same MFMA count & acc size.
// ---------------------------------------------------------------------------
__global__ __launch_bounds__(256) void k1_bcdt_mfma(
    const float* __restrict__ x, const float* __restrict__ w,
    const float* __restrict__ bias, ushort_t* __restrict__ out)
{
    __shared__ __align__(16) short A_lds[192][40];  // [o][k]
    __shared__ __align__(16) short B_lds[128][40];  // [l][k]
    const int l0 = blockIdx.x * 128;
    const int b  = blockIdx.y;
    const int tid  = threadIdx.x;
    const int lane = tid & 63;
    const int wv   = tid >> 6;
    const int wr   = wv >> 1;     // row-half: 96 rows
    const int wc   = wv & 1;      // col-half: 64 cols
    const int lm   = lane & 15;
    const int kg   = lane >> 4;
    const float* xb = x + (size_t)b * D_ * L_;

    f32x4 acc[6][4];
    #pragma unroll
    for (int mi = 0; mi < 6; ++mi)
        #pragma unroll
        for (int nj = 0; nj < 4; ++nj)
            acc[mi][nj] = (f32x4){0.f, 0.f, 0.f, 0.f};

    for (int k0 = 0; k0 < D_; k0 += 32) {
        if (k0) __syncthreads();
        // ---- stage A: w[0..192)[k0..k0+32) ----
        #pragma unroll
        for (int q = 0; q < 3; ++q) {
            int task = q * 256 + tid;
            int o = task >> 2, kk = (task & 3) * 8;
            *(short8*)&A_lds[o][kk] = ld_cvt8(w + (size_t)o * D_ + k0 + kk);
        }
        // ---- stage B: x[k0..k0+32)[l0..l0+128) -> [l][k], float2 loads ----
        {
            int lp = tid & 63;            // l-pair
            int kgs = tid >> 6;           // k-group of 8
            const float* xp = xb + (size_t)(k0 + kgs * 8) * L_ + l0 + lp * 2;
            float2 v[8];
            #pragma unroll
            for (int r = 0; r < 8; ++r)
                v[r] = *reinterpret_cast<const float2*>(xp + (size_t)r * L_);
            short8 s0, s1;
            #pragma unroll
            for (int r = 0; r < 8; ++r) { s0[r] = f2bf(v[r].x); s1[r] = f2bf(v[r].y); }
            *(short8*)&B_lds[lp * 2][kgs * 8]     = s0;
            *(short8*)&B_lds[lp * 2 + 1][kgs * 8] = s1;
        }
        __syncthreads();
        short8 bb[4];
        #pragma unroll
        for (int nj = 0; nj < 4; ++nj)
            bb[nj] = *(const short8*)&B_lds[wc * 64 + nj * 16 + lm][kg * 8];
        #pragma unroll
        for (int mi = 0; mi < 6; ++mi) {
            short8 a = *(const short8*)&A_lds[wr * 96 + mi * 16 + lm][kg * 8];
            #pragma unroll
            for (int nj = 0; nj < 4; ++nj)
                acc[mi][nj] = __builtin_amdgcn_mfma_f32_16x16x32_bf16(
                    a, bb[nj], acc[mi][nj], 0, 0, 0);
        }
    }
    ushort_t* ob = out + (size_t)b * C3_ * L_;
    const int colb = l0 + wc * 64 + lm;
    #pragma unroll
    for (int mi = 0; mi < 6; ++mi) {
        #pragma unroll
        for (int r = 0; r < 4; ++r) {
            int o = wr * 96 + mi * 16 + kg * 4 + r;
            float bv = bias[o];
            #pragma unroll
            for (int nj = 0; nj < 4; ++nj)
                ob[(size_t)o * L_ + colb + nj * 16] =
                    (ushort_t)f2bf(acc[mi][nj][r] + bv);
        }
    }
}

// ---------------------------------------------------------------------------
// K2 fused: blockIdx.x in [0,64)  -> cm channel 64+s  (conv -> cm_bf)
//           blockIdx.x in [64,128)-> ab for s (conv dt -> softmax -> *conv Bm)
// ---------------------------------------------------------------------------
__global__ __launch_bounds__(256) void k2_conv(
    const ushort_t* __restrict__ pre, const float* __restrict__ wdw,
    const float* __restrict__ bdw, ushort_t* __restrict__ cm,
    ushort_t* __restrict__ ab)
{
    __shared__ float sm[66][66];
    __shared__ float red[4];
    const int t   = blockIdx.x;
    const int b   = blockIdx.y;
    const int s   = t & 63;
    const int tid = threadIdx.x;

    for (int i = tid; i < 66 * 66; i += 256) (&sm[0][0])[i] = 0.f;
    __syncthreads();

    if (t < 64) {
        const int c = 64 + s;
        const uint_t* ip32 = reinterpret_cast<const uint_t*>(
            pre + ((size_t)b * C3_ + c) * L_);
        for (int p2 = tid; p2 < 2048; p2 += 256) {
            uint_t v = ip32[p2];
            int q = p2 * 2;
            sm[(q >> 6) + 1][(q & 63) + 1] = bf2f((ushort_t)(v & 0xffffu));
            sm[(q >> 6) + 1][(q & 63) + 2] = bf2f((ushort_t)(v >> 16));
        }
        __syncthreads();
        const float* wp = wdw + c * 9;
        float w00 = wp[0], w01 = wp[1], w02 = wp[2],
              w10 = wp[3], w11 = wp[4], w12 = wp[5],
              w20 = wp[6], w21 = wp[7], w22 = wp[8];
        float bb = bdw[c];
        ushort_t* op = cm + ((size_t)b * S_ + s) * L_;
        for (int p = tid; p < 4096; p += 256) {
            int yy = p >> 6, xx = p & 63;
            float v = bb
                + sm[yy][xx] * w00     + sm[yy][xx + 1] * w01     + sm[yy][xx + 2] * w02
                + sm[yy + 1][xx] * w10 + sm[yy + 1][xx + 1] * w11 + sm[yy + 1][xx + 2] * w12
                + sm[yy + 2][xx] * w20 + sm[yy + 2][xx + 1] * w21 + sm[yy + 2][xx + 2] * w22;
            op[p] = (ushort_t)f2bf(v);
        }
        return;
    }

    const int cd = 128 + s;
    {
        const uint_t* ip32 = reinterpret_cast<const uint_t*>(
            pre + ((size_t)b * C3_ + cd) * L_);
        for (int p2 = tid; p2 < 2048; p2 += 256) {
            uint_t v = ip32[p2];
            int q = p2 * 2;
            sm[(q >> 6) + 1][(q & 63) + 1] = bf2f((ushort_t)(v & 0xffffu));
            sm[(q >> 6) + 1][(q & 63) + 2] = bf2f((ushort_t)(v >> 16));
        }
    }
    __syncthreads();
    float dt[16];
    {
        const float* wp = wdw + cd * 9;
        float w00 = wp[0], w01 = wp[1], w02 = wp[2],
              w10 = wp[3], w11 = wp[4], w12 = wp[5],
              w20 = wp[6], w21 = wp[7], w22 = wp[8];
        float bb = bdw[cd];
        #pragma unroll
        for (int i = 0; i < 16; ++i) {
            int p = tid + 256 * i;
            int yy = p >> 6, xx = p & 63;
            dt[i] = bb
                + sm[yy][xx] * w00     + sm[yy][xx + 1] * w01     + sm[yy][xx + 2] * w02
                + sm[yy + 1][xx] * w10 + sm[yy + 1][xx + 1] * w11 + sm[yy + 1][xx + 2] * w12
                + sm[yy + 2][xx] * w20 + sm[yy + 2][xx + 1] * w21 + sm[yy + 2][xx + 2] * w22;
        }
    }
    float mx = dt[0];
    #pragma unroll
    for (int i = 1; i < 16; ++i) mx = fmaxf(mx, dt[i]);
    #pragma unroll
    for (int off = 32; off >= 1; off >>= 1) mx = fmaxf(mx, __shfl_xor(mx, off, 64));
    if ((tid & 63) == 0) red[tid >> 6] = mx;
    __syncthreads();
    mx = fmaxf(fmaxf(red[0], red[1]), fmaxf(red[2], red[3]));
    float e[16];
    float lsum = 0.f;
    #pragma unroll
    for (int i = 0; i < 16; ++i) { e[i] = expf(dt[i] - mx); lsum += e[i]; }
    #pragma unroll
    for (int off = 32; off >= 1; off >>= 1) lsum += __shfl_xor(lsum, off, 64);
    __syncthreads();
    if ((tid & 63) == 0) red[tid >> 6] = lsum;
    __syncthreads();
    const float inv = 1.f / (red[0] + red[1] + red[2] + red[3]);
    {
        const uint_t* ip32 = reinterpret_cast<const uint_t*>(
            pre + ((size_t)b * C3_ + s) * L_);
        for (int p2 = tid; p2 < 2048; p2 += 256) {
            uint_t v = ip32[p2];
            int q = p2 * 2;
            sm[(q >> 6) + 1][(q & 63) + 1] = bf2f((ushort_t)(v & 0xffffu));
            sm[(q >> 6) + 1][(q & 63) + 2] = bf2f((ushort_t)(v >> 16));
        }
    }
    __syncthreads();
    {
        const float* wp = wdw + s * 9;
        float w00 = wp[0], w01 = wp[1], w02 = wp[2],
              w10 = wp[3], w11 = wp[4], w12 = wp[5],
              w20 = wp[6], w21 = wp[7], w22 = wp[8];
        float bb = bdw[s];
        ushort_t* op = ab + ((size_t)b * S_ + s) * L_;
        #pragma unroll
        for (int i = 0; i < 16; ++i) {
            int p = tid + 256 * i;
            int yy = p >> 6, xx = p & 63;
            float bm = bb
                + sm[yy][xx] * w00     + sm[yy][xx + 1] * w01     + sm[yy][xx + 2] * w02
                + sm[yy + 1][xx] * w10 + sm[yy + 1][xx + 1] * w11 + sm[yy + 1][xx + 2] * w12
                + sm[yy + 2][xx] * w20 + sm[yy + 2][xx + 1] * w21 + sm[yy + 2][xx + 2] * w22;
            op[p] = (ushort_t)f2bf(e[i] * inv * bm);
        }
    }
}

// ---------------------------------------------------------------------------
// K3 (MFMA, no LDS): hp[chunk][b][d][s] += x[b,d,l]*ab[b,s,l] over l-chunk 512
// ---------------------------------------------------------------------------
__global__ __launch_bounds__(256) void k3_hpart_mfma(
    const float* __restrict__ x, const ushort_t* __restrict__ ab,
    float* __restrict__ hp)
{
    const int dt    = blockIdx.x;   // 0..1
    const int b     = blockIdx.y;   // 0..31
    const int chunk = blockIdx.z;   // 0..NCHUNK-1
    const int tid  = threadIdx.x;
    const int lane = tid & 63;
    const int wv   = tid >> 6;
    const int wr   = wv >> 1, wc = wv & 1;
    const int lm   = lane & 15, kg = lane >> 4;
    const int d_base = dt * 128 + wr * 64;
    const int s_base = wc * 32;
    const float*    xb  = x  + (size_t)b * D_ * L_;
    const ushort_t* abb = ab + (size_t)b * S_ * L_;

    f32x4 acc[4][2];
    #pragma unroll
    for (int mi = 0; mi < 4; ++mi)
        #pragma unroll
        for (int nj = 0; nj < 2; ++nj)
            acc[mi][nj] = (f32x4){0.f, 0.f, 0.f, 0.f};

    #pragma unroll 2
    for (int ks = 0; ks < 16; ++ks) {
        const int l = chunk * 512 + ks * 32 + kg * 8;
        short8 bfr[2];
        #pragma unroll
        for (int nj = 0; nj < 2; ++nj)
            bfr[nj] = *reinterpret_cast<const short8*>(
                abb + (size_t)(s_base + nj * 16 + lm) * L_ + l);
        #pragma unroll
        for (int mi = 0; mi < 4; ++mi) {
            short8 a = ld_cvt8(xb + (size_t)(d_base + mi * 16 + lm) * L_ + l);
            #pragma unroll
            for (int nj = 0; nj < 2; ++nj)
                acc[mi][nj] = __builtin_amdgcn_mfma_f32_16x16x32_bf16(
                    a, bfr[nj], acc[mi][nj], 0, 0, 0);
        }
    }
    float* hpo = hp + (size_t)chunk * HOUTSZ + (size_t)b * D_ * S_;
    #pragma unroll
    for (int mi = 0; mi < 4; ++mi)
        #pragma unroll
        for (int r = 0; r < 4; ++r) {
            int d = d_base + mi * 16 + kg * 4 + r;
            #pragma unroll
            for (int nj = 0; nj < 2; ++nj)
                hpo[(size_t)d * S_ + s_base + nj * 16 + lm] = acc[mi][nj][r];
        }
}

// ---------------------------------------------------------------------------
// K4a: h = sum_chunk hp (fused); hz = w_hz @ h + b_hz; g = h2*(silu(z)+D)
// ---------------------------------------------------------------------------
__global__ __launch_bounds__(256) void k4a_gate(
    const float* __restrict__ hp, const float* __restrict__ whz,
    const float* __restrict__ bhz, const float* __restrict__ Dp,
    float* __restrict__ g)
{
    __shared__ float Ah[16][68];
    __shared__ float Az[16][68];
    __shared__ float Bs[16][64];
    const int o0 = blockIdx.x * 64;
    const int b  = blockIdx.y;
    const int tid = threadIdx.x;
    const int tx = tid & 15, ty = tid >> 4;
    float acch[4][4] = {}, accz[4][4] = {};
    const float* hb = hp + (size_t)b * D_ * S_;
    for (int k0 = 0; k0 < D_; k0 += 16) {
        {
            int o = tid & 15, k = tid >> 4;
            #pragma unroll
            for (int i = 0; i < 4; ++i) {
                Ah[k][o + 16 * i] = whz[(size_t)(o0 + o + 16 * i) * D_ + k0 + k];
                Az[k][o + 16 * i] = whz[(size_t)(o0 + o + 16 * i + 256) * D_ + k0 + k];
            }
        }
        {
            int s = tid & 63, k = tid >> 6;
            #pragma unroll
            for (int i = 0; i < 4; ++i) {
                float sum = 0.f;
                #pragma unroll
                for (int c = 0; c < NCHUNK; ++c)
                    sum += hb[(size_t)c * HOUTSZ + (size_t)(k0 + k + 4 * i) * S_ + s];
                Bs[k + 4 * i][s] = sum;
            }
        }
        __syncthreads();
        #pragma unroll
        for (int k = 0; k < 16; ++k) {
            float ah[4], az[4], bb[4];
            #pragma unroll
            for (int i = 0; i < 4; ++i) { ah[i] = Ah[k][ty * 4 + i]; az[i] = Az[k][ty * 4 + i]; }
            #pragma unroll
            for (int j = 0; j < 4; ++j) bb[j] = Bs[k][tx * 4 + j];
            #pragma unroll
            for (int i = 0; i < 4; ++i)
                #pragma unroll
                for (int j = 0; j < 4; ++j) {
                    acch[i][j] += ah[i] * bb[j];
                    accz[i][j] += az[i] * bb[j];
                }
        }
        __syncthreads();
    }
    const float dp = Dp[0];
    #pragma unroll
    for (int i = 0; i < 4; ++i) {
        int o = o0 + ty * 4 + i;
        float bh = bhz[o], bz = bhz[o + 256];
        #pragma unroll
        for (int j = 0; j < 4; ++j) {
            float h2 = acch[i][j] + bh;
            float z  = accz[i][j] + bz;
            float sil = z / (1.f + expf(-z));
            g[((size_t)b * D_ + o) * S_ + tx * 4 + j] = h2 * (sil + dp);
        }
    }
}

// ---------------------------------------------------------------------------
// K4b: hout = w_out @ g + b_out -> d_out (output 1)
// ---------------------------------------------------------------------------
__global__ __launch_bounds__(256) void k4b_hout(
    const float* __restrict__ g, const float* __restrict__ wout,
    const float* __restrict__ bout, float* __restrict__ hout)
{
    __shared__ float At[16][68];
    __shared__ float Bs[16][64];
    const int o0 = blockIdx.x * 64;
    const int b  = blockIdx.y;
    const int tid = threadIdx.x;
    const int tx = tid & 15, ty = tid >> 4;
    float acc[4][4] = {};
    const float* gb = g + (size_t)b * D_ * S_;
    for (int k0 = 0; k0 < D_; k0 += 16) {
        {
            int o = tid & 15, k = tid >> 4;
            #pragma unroll
            for (int i = 0; i < 4; ++i)
                At[k][o + 16 * i] = wout[(size_t)(o0 + o + 16 * i) * D_ + k0 + k];
        }
        {
            int s = tid & 63, k = tid >> 6;
            #pragma unroll
            for (int i = 0; i < 4; ++i)
                Bs[k + 4 * i][s] = gb[(size_t)(k0 + k + 4 * i) * S_ + s];
        }
        __syncthreads();
        #pragma unroll
        for (int k = 0; k < 16; ++k) {
            float a[4], bb[4];
            #pragma unroll
            for (int i = 0; i < 4; ++i) a[i] = At[k][ty * 4 + i];
            #pragma unroll
            for (int j = 0; j < 4; ++j) bb[j] = Bs[k][tx * 4 + j];
            #pragma unroll
            for (int i = 0; i < 4; ++i)
                #pragma unroll
                for (int j = 0; j < 4; ++j)
                    acc[i][j] += a[i] * bb[j];
        }
        __syncthreads();
    }
    #pragma unroll
    for (int i = 0; i < 4; ++i) {
        int o = o0 + ty * 4 + i;
        float bv = bout[o];
        #pragma unroll
        for (int j = 0; j < 4; ++j)
            hout[((size_t)b * D_ + o) * S_ + tx * 4 + j] = acc[i][j] + bv;
    }
}

// ---------------------------------------------------------------------------
// K5 (MFMA): y[b][d][l] = sum_s hout[b][d][s] * cm_bf[b][s][l]  (R5 version)
// ---------------------------------------------------------------------------
__global__ __launch_bounds__(256) void k5_expand_mfma(
    const float* __restrict__ hout, const ushort_t* __restrict__ cm,
    float* __restrict__ y)
{
    __shared__ __align__(16) short A_lds[64][72];   // [d][s]
    __shared__ __align__(16) short B_lds[128][72];  // [l][s]
    const int l0 = blockIdx.x * 128;
    const int d0 = blockIdx.y * 64;
    const int b  = blockIdx.z;
    const int tid  = threadIdx.x;
    const int lane = tid & 63;
    const int wv   = tid >> 6;
    const int lm   = lane & 15, kg = lane >> 4;

    #pragma unroll
    for (int q = 0; q < 2; ++q) {
        int task = q * 256 + tid;
        int d = task >> 3, sg = (task & 7) * 8;
        *(short8*)&A_lds[d][sg] = ld_cvt8(hout + ((size_t)b * D_ + d0 + d) * S_ + sg);
    }
    #pragma unroll
    for (int q = 0; q < 4; ++q) {
        int l = tid & 127;
        int sg = (q * 2 + (tid >> 7)) * 8;
        const ushort_t* cp = cm + ((size_t)b * S_ + sg) * L_ + l0 + l;
        short8 s;
        #pragma unroll
        for (int r = 0; r < 8; ++r) s[r] = (short)cp[(size_t)r * L_];
        *(short8*)&B_lds[l][sg] = s;
    }
    __syncthreads();

    f32x4 acc[4][2];
    #pragma unroll
    for (int mi = 0; mi < 4; ++mi)
        #pragma unroll
        for (int nj = 0; nj < 2; ++nj)
            acc[mi][nj] = (f32x4){0.f, 0.f, 0.f, 0.f};
    #pragma unroll
    for (int ks = 0; ks < 2; ++ks) {
        short8 bb[2];
        #pragma unroll
        for (int nj = 0; nj < 2; ++nj)
            bb[nj] = *(const short8*)&B_lds[wv * 32 + nj * 16 + lm][ks * 32 + kg * 8];
        #pragma unroll
        for (int mi = 0; mi < 4; ++mi) {
            short8 a = *(const short8*)&A_lds[mi * 16 + lm][ks * 32 + kg * 8];
            #pragma unroll
            for (int nj = 0; nj < 2; ++nj)
                acc[mi][nj] = __builtin_amdgcn_mfma_f32_16x16x32_bf16(
                    a, bb[nj], acc[mi][nj], 0, 0, 0);
        }
    }
    const int col = l0 + wv * 32 + lm;
    #pragma unroll
    for (int mi = 0; mi < 4; ++mi)
        #pragma unroll
        for (int r = 0; r < 4; ++r)
            #pragma unroll
            for (int nj = 0; nj < 2; ++nj)
                y[((size_t)b * D_ + d0 + mi * 16 + kg * 4 + r) * L_ + col + nj * 16]
                    = acc[mi][nj][r];
}

// ---------------------------------------------------------------------------
extern "C" void kernel_launch(void* const* d_in, const int* in_sizes, int n_in,
                              void* d_out, int out_size, void* d_ws, size_t ws_size,
                              hipStream_t stream)
{
    const float* x      = (const float*)d_in[0];
    const float* w_bcdt = (const float*)d_in[3];
    const float* b_bcdt = (const float*)d_in[4];
    const float* w_dw   = (const float*)d_in[5];
    const float* b_dw   = (const float*)d_in[6];
    const float* w_hz   = (const float*)d_in[7];
    const float* b_hz   = (const float*)d_in[8];
    const float* w_out  = (const float*)d_in[9];
    const float* b_out  = (const float*)d_in[10];
    // d_in[11] = A_param: constant along softmax axis L -> cancels, unused
    const float* Dp     = (const float*)d_in[12];

    char* base = (char*)d_ws;
    ushort_t* pre_bf = (ushort_t*)(base);                    // 50.3 MB
    ushort_t* ab_bf  = (ushort_t*)(base + 50331648);         // 16.8 MB
    ushort_t* cm_bf  = (ushort_t*)(base + 67108864);         // 16.8 MB
    float*    hp     = (float*)   (base + 83886080);         // 8*2 MB = 16.8 MB
    float*    g      = (float*)   (base + 100663296);        //  2.1 MB

    float* y    = (float*)d_out;
    float* hout = (float*)d_out + YSZ;

    k1_bcdt_mfma  <<<dim3(32, 32),        256, 0, stream>>>(x, w_bcdt, b_bcdt, pre_bf);
    k2_conv       <<<dim3(128, 32),       256, 0, stream>>>(pre_bf, w_dw, b_dw, cm_bf, ab_bf);
    k3_hpart_mfma <<<dim3(2, 32, NCHUNK), 256, 0, stream>>>(x, ab_bf, hp);
    k4a_gate      <<<dim3(4, 32),         256, 0, stream>>>(hp, w_hz, b_hz, Dp, g);
    k4b_hout      <<<dim3(4, 32),         256, 0, stream>>>(g, w_out, b_out, hout);
    k5_expand_mfma<<<dim3(32, 4, 32),     256, 0, stream>>>(hout, cm_bf, y);
}

// Round 10
// 212.127 us; speedup vs baseline: 1.2552x; 1.0024x over previous
//
#include <hip/hip_runtime.h>
#include <math.h>

#define B_  32
#define D_  256
#define L_  4096
#define S_  64
#define C3_ 192

#define YSZ    ((size_t)B_ * D_ * L_)   /* 33554432 */
#define HOUTSZ ((size_t)B_ * D_ * S_)   /* 524288  */
#define NCHUNK 8

typedef __attribute__((ext_vector_type(8))) short short8;
typedef __attribute__((ext_vector_type(4))) float f32x4;
typedef unsigned short ushort_t;
typedef unsigned int uint_t;

// hardware bf16 convert (RNE)
__device__ __forceinline__ short f2bf(float f) {
    __bf16 h = (__bf16)f;
    return __builtin_bit_cast(short, h);
}
__device__ __forceinline__ float bf2f(ushort_t u) {
    return __uint_as_float((uint_t)u << 16);
}
__device__ __forceinline__ short8 ld_cvt8(const float* p) {
    const float4* q = reinterpret_cast<const float4*>(p);
    float4 p0 = q[0], p1 = q[1];
    short8 s;
    s[0] = f2bf(p0.x); s[1] = f2bf(p0.y); s[2] = f2bf(p0.z); s[3] = f2bf(p0.w);
    s[4] = f2bf(p1.x); s[5] = f2bf(p1.y); s[6] = f2bf(p1.z); s[7] = f2bf(p1.w);
    return s;
}

// ---------------------------------------------------------------------------
// K1 (MFMA): pre_bf[b][o][l] = bf16( b_bcdt[o] + sum_d w[o][d] * x[b][d][l] )
// R9 structure + T14 async-STAGE split: global loads for step t+1 issued
// BEFORE the MFMA phase of step t, so HBM/L3 latency hides under compute.
// Phases: {cvt+ds_write(t) | barrier | load(t+1) ; ds_read+MFMA(t) | barrier}
// ---------------------------------------------------------------------------
__global__ __launch_bounds__(256) void k1_bcdt_mfma(
    const float* __restrict__ x, const float* __restrict__ w,
    const float* __restrict__ bias, ushort_t* __restrict__ out)
{
    __shared__ __align__(16) short A_lds[192][40];  // [o][k]
    __shared__ __align__(16) short B_lds[128][40];  // [l][k]
    const int l0 = blockIdx.x * 128;
    const int b  = blockIdx.y;
    const int tid  = threadIdx.x;
    const int lane = tid & 63;
    const int wv   = tid >> 6;
    const int wr   = wv >> 1;     // row-half: 96 rows
    const int wc   = wv & 1;      // col-half: 64 cols
    const int lm   = lane & 15;
    const int kg   = lane >> 4;
    const int lp   = tid & 63;    // staging: l-pair
    const int kgs  = tid >> 6;    // staging: k-group of 8
    const int oA   = tid >> 2;    // staging A: output row (w/ +256-task offset)
    const int kkA  = (tid & 3) * 8;
    const float* xb = x + (size_t)b * D_ * L_;

    f32x4 acc[6][4];
    #pragma unroll
    for (int mi = 0; mi < 6; ++mi)
        #pragma unroll
        for (int nj = 0; nj < 4; ++nj)
            acc[mi][nj] = (f32x4){0.f, 0.f, 0.f, 0.f};

    float2 vx[8];        // in-flight x for current write-phase
    float4 vw[3][2];     // in-flight w

    auto LOAD = [&](int step) {
        const int k0 = step * 32;
        const float* xp = xb + (size_t)(k0 + kgs * 8) * L_ + l0 + lp * 2;
        #pragma unroll
        for (int r = 0; r < 8; ++r)
            vx[r] = *reinterpret_cast<const float2*>(xp + (size_t)r * L_);
        #pragma unroll
        for (int q = 0; q < 3; ++q) {
            const float4* wp = reinterpret_cast<const float4*>(
                w + (size_t)(q * 64 + oA) * D_ + k0 + kkA);
            vw[q][0] = wp[0];
            vw[q][1] = wp[1];
        }
    };

    LOAD(0);
    for (int step = 0; step < 8; ++step) {
        if (step) __syncthreads();   // prior reads done before overwrite
        // ---- cvt + ds_write (consumes vx/vw) ----
        #pragma unroll
        for (int q = 0; q < 3; ++q) {
            float4 p0 = vw[q][0], p1 = vw[q][1];
            short8 s;
            s[0] = f2bf(p0.x); s[1] = f2bf(p0.y); s[2] = f2bf(p0.z); s[3] = f2bf(p0.w);
            s[4] = f2bf(p1.x); s[5] = f2bf(p1.y); s[6] = f2bf(p1.z); s[7] = f2bf(p1.w);
            *(short8*)&A_lds[q * 64 + oA][kkA] = s;
        }
        {
            short8 s0, s1;
            #pragma unroll
            for (int r = 0; r < 8; ++r) { s0[r] = f2bf(vx[r].x); s1[r] = f2bf(vx[r].y); }
            *(short8*)&B_lds[lp * 2][kgs * 8]     = s0;
            *(short8*)&B_lds[lp * 2 + 1][kgs * 8] = s1;
        }
        __syncthreads();             // writes visible
        // ---- issue next step's loads BEFORE compute (T14) ----
        if (step < 7) LOAD(step + 1);
        // ---- ds_read + MFMA ----
        short8 bb[4];
        #pragma unroll
        for (int nj = 0; nj < 4; ++nj)
            bb[nj] = *(const short8*)&B_lds[wc * 64 + nj * 16 + lm][kg * 8];
        #pragma unroll
        for (int mi = 0; mi < 6; ++mi) {
            short8 a = *(const short8*)&A_lds[wr * 96 + mi * 16 + lm][kg * 8];
            #pragma unroll
            for (int nj = 0; nj < 4; ++nj)
                acc[mi][nj] = __builtin_amdgcn_mfma_f32_16x16x32_bf16(
                    a, bb[nj], acc[mi][nj], 0, 0, 0);
        }
    }
    ushort_t* ob = out + (size_t)b * C3_ * L_;
    const int colb = l0 + wc * 64 + lm;
    #pragma unroll
    for (int mi = 0; mi < 6; ++mi) {
        #pragma unroll
        for (int r = 0; r < 4; ++r) {
            int o = wr * 96 + mi * 16 + kg * 4 + r;
            float bv = bias[o];
            #pragma unroll
            for (int nj = 0; nj < 4; ++nj)
                ob[(size_t)o * L_ + colb + nj * 16] =
                    (ushort_t)f2bf(acc[mi][nj][r] + bv);
        }
    }
}

// ---------------------------------------------------------------------------
// K2 fused: blockIdx.x in [0,64)  -> cm channel 64+s  (conv -> cm_bf)
//           blockIdx.x in [64,128)-> ab for s (conv dt -> softmax -> *conv Bm)
// ---------------------------------------------------------------------------
__global__ __launch_bounds__(256) void k2_conv(
    const ushort_t* __restrict__ pre, const float* __restrict__ wdw,
    const float* __restrict__ bdw, ushort_t* __restrict__ cm,
    ushort_t* __restrict__ ab)
{
    __shared__ float sm[66][66];
    __shared__ float red[4];
    const int t   = blockIdx.x;
    const int b   = blockIdx.y;
    const int s   = t & 63;
    const int tid = threadIdx.x;

    for (int i = tid; i < 66 * 66; i += 256) (&sm[0][0])[i] = 0.f;
    __syncthreads();

    if (t < 64) {
        const int c = 64 + s;
        const uint_t* ip32 = reinterpret_cast<const uint_t*>(
            pre + ((size_t)b * C3_ + c) * L_);
        for (int p2 = tid; p2 < 2048; p2 += 256) {
            uint_t v = ip32[p2];
            int q = p2 * 2;
            sm[(q >> 6) + 1][(q & 63) + 1] = bf2f((ushort_t)(v & 0xffffu));
            sm[(q >> 6) + 1][(q & 63) + 2] = bf2f((ushort_t)(v >> 16));
        }
        __syncthreads();
        const float* wp = wdw + c * 9;
        float w00 = wp[0], w01 = wp[1], w02 = wp[2],
              w10 = wp[3], w11 = wp[4], w12 = wp[5],
              w20 = wp[6], w21 = wp[7], w22 = wp[8];
        float bb = bdw[c];
        ushort_t* op = cm + ((size_t)b * S_ + s) * L_;
        for (int p = tid; p < 4096; p += 256) {
            int yy = p >> 6, xx = p & 63;
            float v = bb
                + sm[yy][xx] * w00     + sm[yy][xx + 1] * w01     + sm[yy][xx + 2] * w02
                + sm[yy + 1][xx] * w10 + sm[yy + 1][xx + 1] * w11 + sm[yy + 1][xx + 2] * w12
                + sm[yy + 2][xx] * w20 + sm[yy + 2][xx + 1] * w21 + sm[yy + 2][xx + 2] * w22;
            op[p] = (ushort_t)f2bf(v);
        }
        return;
    }

    const int cd = 128 + s;
    {
        const uint_t* ip32 = reinterpret_cast<const uint_t*>(
            pre + ((size_t)b * C3_ + cd) * L_);
        for (int p2 = tid; p2 < 2048; p2 += 256) {
            uint_t v = ip32[p2];
            int q = p2 * 2;
            sm[(q >> 6) + 1][(q & 63) + 1] = bf2f((ushort_t)(v & 0xffffu));
            sm[(q >> 6) + 1][(q & 63) + 2] = bf2f((ushort_t)(v >> 16));
        }
    }
    __syncthreads();
    float dt[16];
    {
        const float* wp = wdw + cd * 9;
        float w00 = wp[0], w01 = wp[1], w02 = wp[2],
              w10 = wp[3], w11 = wp[4], w12 = wp[5],
              w20 = wp[6], w21 = wp[7], w22 = wp[8];
        float bb = bdw[cd];
        #pragma unroll
        for (int i = 0; i < 16; ++i) {
            int p = tid + 256 * i;
            int yy = p >> 6, xx = p & 63;
            dt[i] = bb
                + sm[yy][xx] * w00     + sm[yy][xx + 1] * w01     + sm[yy][xx + 2] * w02
                + sm[yy + 1][xx] * w10 + sm[yy + 1][xx + 1] * w11 + sm[yy + 1][xx + 2] * w12
                + sm[yy + 2][xx] * w20 + sm[yy + 2][xx + 1] * w21 + sm[yy + 2][xx + 2] * w22;
        }
    }
    float mx = dt[0];
    #pragma unroll
    for (int i = 1; i < 16; ++i) mx = fmaxf(mx, dt[i]);
    #pragma unroll
    for (int off = 32; off >= 1; off >>= 1) mx = fmaxf(mx, __shfl_xor(mx, off, 64));
    if ((tid & 63) == 0) red[tid >> 6] = mx;
    __syncthreads();
    mx = fmaxf(fmaxf(red[0], red[1]), fmaxf(red[2], red[3]));
    float e[16];
    float lsum = 0.f;
    #pragma unroll
    for (int i = 0; i < 16; ++i) { e[i] = expf(dt[i] - mx); lsum += e[i]; }
    #pragma unroll
    for (int off = 32; off >= 1; off >>= 1) lsum += __shfl_xor(lsum, off, 64);
    __syncthreads();
    if ((tid & 63) == 0) red[tid >> 6] = lsum;
    __syncthreads();
    const float inv = 1.f / (red[0] + red[1] + red[2] + red[3]);
    {
        const uint_t* ip32 = reinterpret_cast<const uint_t*>(
            pre + ((size_t)b * C3_ + s) * L_);
        for (int p2 = tid; p2 < 2048; p2 += 256) {
            uint_t v = ip32[p2];
            int q = p2 * 2;
            sm[(q >> 6) + 1][(q & 63) + 1] = bf2f((ushort_t)(v & 0xffffu));
            sm[(q >> 6) + 1][(q & 63) + 2] = bf2f((ushort_t)(v >> 16));
        }
    }
    __syncthreads();
    {
        const float* wp = wdw + s * 9;
        float w00 = wp[0], w01 = wp[1], w02 = wp[2],
              w10 = wp[3], w11 = wp[4], w12 = wp[5],
              w20 = wp[6], w21 = wp[7], w22 = wp[8];
        float bb = bdw[s];
        ushort_t* op = ab + ((size_t)b * S_ + s) * L_;
        #pragma unroll
        for (int i = 0; i < 16; ++i) {
            int p = tid + 256 * i;
            int yy = p >> 6, xx = p & 63;
            float bm = bb
                + sm[yy][xx] * w00     + sm[yy][xx + 1] * w01     + sm[yy][xx + 2] * w02
                + sm[yy + 1][xx] * w10 + sm[yy + 1][xx + 1] * w11 + sm[yy + 1][xx + 2] * w12
                + sm[yy + 2][xx] * w20 + sm[yy + 2][xx + 1] * w21 + sm[yy + 2][xx + 2] * w22;
            op[p] = (ushort_t)f2bf(e[i] * inv * bm);
        }
    }
}

// ---------------------------------------------------------------------------
// K3 (MFMA, no LDS): hp[chunk][b][d][s] += x[b,d,l]*ab[b,s,l] over l-chunk 512
// ---------------------------------------------------------------------------
__global__ __launch_bounds__(256) void k3_hpart_mfma(
    const float* __restrict__ x, const ushort_t* __restrict__ ab,
    float* __restrict__ hp)
{
    const int dt    = blockIdx.x;   // 0..1
    const int b     = blockIdx.y;   // 0..31
    const int chunk = blockIdx.z;   // 0..NCHUNK-1
    const int tid  = threadIdx.x;
    const int lane = tid & 63;
    const int wv   = tid >> 6;
    const int wr   = wv >> 1, wc = wv & 1;
    const int lm   = lane & 15, kg = lane >> 4;
    const int d_base = dt * 128 + wr * 64;
    const int s_base = wc * 32;
    const float*    xb  = x  + (size_t)b * D_ * L_;
    const ushort_t* abb = ab + (size_t)b * S_ * L_;

    f32x4 acc[4][2];
    #pragma unroll
    for (int mi = 0; mi < 4; ++mi)
        #pragma unroll
        for (int nj = 0; nj < 2; ++nj)
            acc[mi][nj] = (f32x4){0.f, 0.f, 0.f, 0.f};

    #pragma unroll 2
    for (int ks = 0; ks < 16; ++ks) {
        const int l = chunk * 512 + ks * 32 + kg * 8;
        short8 bfr[2];
        #pragma unroll
        for (int nj = 0; nj < 2; ++nj)
            bfr[nj] = *reinterpret_cast<const short8*>(
                abb + (size_t)(s_base + nj * 16 + lm) * L_ + l);
        #pragma unroll
        for (int mi = 0; mi < 4; ++mi) {
            short8 a = ld_cvt8(xb + (size_t)(d_base + mi * 16 + lm) * L_ + l);
            #pragma unroll
            for (int nj = 0; nj < 2; ++nj)
                acc[mi][nj] = __builtin_amdgcn_mfma_f32_16x16x32_bf16(
                    a, bfr[nj], acc[mi][nj], 0, 0, 0);
        }
    }
    float* hpo = hp + (size_t)chunk * HOUTSZ + (size_t)b * D_ * S_;
    #pragma unroll
    for (int mi = 0; mi < 4; ++mi)
        #pragma unroll
        for (int r = 0; r < 4; ++r) {
            int d = d_base + mi * 16 + kg * 4 + r;
            #pragma unroll
            for (int nj = 0; nj < 2; ++nj)
                hpo[(size_t)d * S_ + s_base + nj * 16 + lm] = acc[mi][nj][r];
        }
}

// ---------------------------------------------------------------------------
// K4a: h = sum_chunk hp (fused); hz = w_hz @ h + b_hz; g = h2*(silu(z)+D)
// ---------------------------------------------------------------------------
__global__ __launch_bounds__(256) void k4a_gate(
    const float* __restrict__ hp, const float* __restrict__ whz,
    const float* __restrict__ bhz, const float* __restrict__ Dp,
    float* __restrict__ g)
{
    __shared__ float Ah[16][68];
    __shared__ float Az[16][68];
    __shared__ float Bs[16][64];
    const int o0 = blockIdx.x * 64;
    const int b  = blockIdx.y;
    const int tid = threadIdx.x;
    const int tx = tid & 15, ty = tid >> 4;
    float acch[4][4] = {}, accz[4][4] = {};
    const float* hb = hp + (size_t)b * D_ * S_;
    for (int k0 = 0; k0 < D_; k0 += 16) {
        {
            int o = tid & 15, k = tid >> 4;
            #pragma unroll
            for (int i = 0; i < 4; ++i) {
                Ah[k][o + 16 * i] = whz[(size_t)(o0 + o + 16 * i) * D_ + k0 + k];
                Az[k][o + 16 * i] = whz[(size_t)(o0 + o + 16 * i + 256) * D_ + k0 + k];
            }
        }
        {
            int s = tid & 63, k = tid >> 6;
            #pragma unroll
            for (int i = 0; i < 4; ++i) {
                float sum = 0.f;
                #pragma unroll
                for (int c = 0; c < NCHUNK; ++c)
                    sum += hb[(size_t)c * HOUTSZ + (size_t)(k0 + k + 4 * i) * S_ + s];
                Bs[k + 4 * i][s] = sum;
            }
        }
        __syncthreads();
        #pragma unroll
        for (int k = 0; k < 16; ++k) {
            float ah[4], az[4], bb[4];
            #pragma unroll
            for (int i = 0; i < 4; ++i) { ah[i] = Ah[k][ty * 4 + i]; az[i] = Az[k][ty * 4 + i]; }
            #pragma unroll
            for (int j = 0; j < 4; ++j) bb[j] = Bs[k][tx * 4 + j];
            #pragma unroll
            for (int i = 0; i < 4; ++i)
                #pragma unroll
                for (int j = 0; j < 4; ++j) {
                    acch[i][j] += ah[i] * bb[j];
                    accz[i][j] += az[i] * bb[j];
                }
        }
        __syncthreads();
    }
    const float dp = Dp[0];
    #pragma unroll
    for (int i = 0; i < 4; ++i) {
        int o = o0 + ty * 4 + i;
        float bh = bhz[o], bz = bhz[o + 256];
        #pragma unroll
        for (int j = 0; j < 4; ++j) {
            float h2 = acch[i][j] + bh;
            float z  = accz[i][j] + bz;
            float sil = z / (1.f + expf(-z));
            g[((size_t)b * D_ + o) * S_ + tx * 4 + j] = h2 * (sil + dp);
        }
    }
}

// ---------------------------------------------------------------------------
// K4b: hout = w_out @ g + b_out -> d_out (output 1)
// ---------------------------------------------------------------------------
__global__ __launch_bounds__(256) void k4b_hout(
    const float* __restrict__ g, const float* __restrict__ wout,
    const float* __restrict__ bout, float* __restrict__ hout)
{
    __shared__ float At[16][68];
    __shared__ float Bs[16][64];
    const int o0 = blockIdx.x * 64;
    const int b  = blockIdx.y;
    const int tid = threadIdx.x;
    const int tx = tid & 15, ty = tid >> 4;
    float acc[4][4] = {};
    const float* gb = g + (size_t)b * D_ * S_;
    for (int k0 = 0; k0 < D_; k0 += 16) {
        {
            int o = tid & 15, k = tid >> 4;
            #pragma unroll
            for (int i = 0; i < 4; ++i)
                At[k][o + 16 * i] = wout[(size_t)(o0 + o + 16 * i) * D_ + k0 + k];
        }
        {
            int s = tid & 63, k = tid >> 6;
            #pragma unroll
            for (int i = 0; i < 4; ++i)
                Bs[k + 4 * i][s] = gb[(size_t)(k0 + k + 4 * i) * S_ + s];
        }
        __syncthreads();
        #pragma unroll
        for (int k = 0; k < 16; ++k) {
            float a[4], bb[4];
            #pragma unroll
            for (int i = 0; i < 4; ++i) a[i] = At[k][ty * 4 + i];
            #pragma unroll
            for (int j = 0; j < 4; ++j) bb[j] = Bs[k][tx * 4 + j];
            #pragma unroll
            for (int i = 0; i < 4; ++i)
                #pragma unroll
                for (int j = 0; j < 4; ++j)
                    acc[i][j] += a[i] * bb[j];
        }
        __syncthreads();
    }
    #pragma unroll
    for (int i = 0; i < 4; ++i) {
        int o = o0 + ty * 4 + i;
        float bv = bout[o];
        #pragma unroll
        for (int j = 0; j < 4; ++j)
            hout[((size_t)b * D_ + o) * S_ + tx * 4 + j] = acc[i][j] + bv;
    }
}

// ---------------------------------------------------------------------------
// K5 (MFMA): y[b][d][l] = sum_s hout[b][d][s] * cm_bf[b][s][l]  (R5 version)
// ---------------------------------------------------------------------------
__global__ __launch_bounds__(256) void k5_expand_mfma(
    const float* __restrict__ hout, const ushort_t* __restrict__ cm,
    float* __restrict__ y)
{
    __shared__ __align__(16) short A_lds[64][72];   // [d][s]
    __shared__ __align__(16) short B_lds[128][72];  // [l][s]
    const int l0 = blockIdx.x * 128;
    const int d0 = blockIdx.y * 64;
    const int b  = blockIdx.z;
    const int tid  = threadIdx.x;
    const int lane = tid & 63;
    const int wv   = tid >> 6;
    const int lm   = lane & 15, kg = lane >> 4;

    #pragma unroll
    for (int q = 0; q < 2; ++q) {
        int task = q * 256 + tid;
        int d = task >> 3, sg = (task & 7) * 8;
        *(short8*)&A_lds[d][sg] = ld_cvt8(hout + ((size_t)b * D_ + d0 + d) * S_ + sg);
    }
    #pragma unroll
    for (int q = 0; q < 4; ++q) {
        int l = tid & 127;
        int sg = (q * 2 + (tid >> 7)) * 8;
        const ushort_t* cp = cm + ((size_t)b * S_ + sg) * L_ + l0 + l;
        short8 s;
        #pragma unroll
        for (int r = 0; r < 8; ++r) s[r] = (short)cp[(size_t)r * L_];
        *(short8*)&B_lds[l][sg] = s;
    }
    __syncthreads();

    f32x4 acc[4][2];
    #pragma unroll
    for (int mi = 0; mi < 4; ++mi)
        #pragma unroll
        for (int nj = 0; nj < 2; ++nj)
            acc[mi][nj] = (f32x4){0.f, 0.f, 0.f, 0.f};
    #pragma unroll
    for (int ks = 0; ks < 2; ++ks) {
        short8 bb[2];
        #pragma unroll
        for (int nj = 0; nj < 2; ++nj)
            bb[nj] = *(const short8*)&B_lds[wv * 32 + nj * 16 + lm][ks * 32 + kg * 8];
        #pragma unroll
        for (int mi = 0; mi < 4; ++mi) {
            short8 a = *(const short8*)&A_lds[mi * 16 + lm][ks * 32 + kg * 8];
            #pragma unroll
            for (int nj = 0; nj < 2; ++nj)
                acc[mi][nj] = __builtin_amdgcn_mfma_f32_16x16x32_bf16(
                    a, bb[nj], acc[mi][nj], 0, 0, 0);
        }
    }
    const int col = l0 + wv * 32 + lm;
    #pragma unroll
    for (int mi = 0; mi < 4; ++mi)
        #pragma unroll
        for (int r = 0; r < 4; ++r)
            #pragma unroll
            for (int nj = 0; nj < 2; ++nj)
                y[((size_t)b * D_ + d0 + mi * 16 + kg * 4 + r) * L_ + col + nj * 16]
                    = acc[mi][nj][r];
}

// ---------------------------------------------------------------------------
extern "C" void kernel_launch(void* const* d_in, const int* in_sizes, int n_in,
                              void* d_out, int out_size, void* d_ws, size_t ws_size,
                              hipStream_t stream)
{
    const float* x      = (const float*)d_in[0];
    const float* w_bcdt = (const float*)d_in[3];
    const float* b_bcdt = (const float*)d_in[4];
    const float* w_dw   = (const float*)d_in[5];
    const float* b_dw   = (const float*)d_in[6];
    const float* w_hz   = (const float*)d_in[7];
    const float* b_hz   = (const float*)d_in[8];
    const float* w_out  = (const float*)d_in[9];
    const float* b_out  = (const float*)d_in[10];
    // d_in[11] = A_param: constant along softmax axis L -> cancels, unused
    const float* Dp     = (const float*)d_in[12];

    char* base = (char*)d_ws;
    ushort_t* pre_bf = (ushort_t*)(base);                    // 50.3 MB
    ushort_t* ab_bf  = (ushort_t*)(base + 50331648);         // 16.8 MB
    ushort_t* cm_bf  = (ushort_t*)(base + 67108864);         // 16.8 MB
    float*    hp     = (float*)   (base + 83886080);         // 8*2 MB = 16.8 MB
    float*    g      = (float*)   (base + 100663296);        //  2.1 MB

    float* y    = (float*)d_out;
    float* hout = (float*)d_out + YSZ;

    k1_bcdt_mfma  <<<dim3(32, 32),        256, 0, stream>>>(x, w_bcdt, b_bcdt, pre_bf);
    k2_conv       <<<dim3(128, 32),       256, 0, stream>>>(pre_bf, w_dw, b_dw, cm_bf, ab_bf);
    k3_hpart_mfma <<<dim3(2, 32, NCHUNK), 256, 0, stream>>>(x, ab_bf, hp);
    k4a_gate      <<<dim3(4, 32),         256, 0, stream>>>(hp, w_hz, b_hz, Dp, g);
    k4b_hout      <<<dim3(4, 32),         256, 0, stream>>>(g, w_out, b_out, hout);
    k5_expand_mfma<<<dim3(32, 4, 32),     256, 0, stream>>>(hout, cm_bf, y);
}